// Round 18
// baseline (274.581 us; speedup 1.0000x reference)
//
#include <hip/hip_runtime.h>
#include <hip/hip_bf16.h>
#include <cstdint>

#define TB 256

typedef __attribute__((ext_vector_type(8))) short bf16x8;
typedef __attribute__((ext_vector_type(4))) float f32x4;
typedef __attribute__((ext_vector_type(2))) float f32x2;

__device__ __forceinline__ float lrelu_exp(float e){
  e = e > 0.0f ? e : 0.2f * e;
  return __expf(e);
}
__device__ __forceinline__ unsigned short f2bf(float f){
  unsigned u = __float_as_uint(f);
  u = (u + 0x7fffu + ((u >> 16) & 1u)) >> 16;   // RNE
  return (unsigned short)u;
}
__device__ __forceinline__ float lof(unsigned u){ return __uint_as_float(u << 16); }
__device__ __forceinline__ float hif(unsigned u){ return __uint_as_float(u & 0xffff0000u); }
__device__ __forceinline__ unsigned pack2(float a, float b){
  return (unsigned)f2bf(a) | ((unsigned)f2bf(b) << 16);
}

// ================= CSR build via 2-level bucket sort (LDS atomics only) =================

__global__ __launch_bounds__(256) void k_cnt(const int* __restrict__ ei, int E, int n,
                                             int* __restrict__ counts, int B, int NBK){
  __shared__ int h[512];
  int t = threadIdx.x;
  for (int i = t; i < NBK; i += 256) h[i] = 0;
  __syncthreads();
  int base = blockIdx.x * 8192;
  int end = base + 8192; if (end > E) end = E;
  for (int e = base + t; e < end; e += 256){
    int d = ei[E + e];
    if ((unsigned)d < (unsigned)n) atomicAdd(&h[d >> 8], 1);
  }
  __syncthreads();
  for (int i = t; i < NBK; i += 256) counts[i * B + blockIdx.x] = h[i];
}

__global__ __launch_bounds__(256) void k_s1(int* __restrict__ counts, int total, int* __restrict__ partials){
  __shared__ int sums[256];
  int t = threadIdx.x;
  int base = blockIdx.x * 2048 + t * 8;
  int v[8]; int s = 0;
  #pragma unroll
  for (int i = 0; i < 8; ++i){ int idx = base + i; v[i] = (idx < total) ? counts[idx] : 0; s += v[i]; }
  sums[t] = s;
  __syncthreads();
  for (int off = 1; off < 256; off <<= 1){
    int add = (t >= off) ? sums[t - off] : 0;
    __syncthreads();
    sums[t] += add;
    __syncthreads();
  }
  int run = sums[t] - s;
  if (t == 255) partials[blockIdx.x] = sums[t];
  #pragma unroll
  for (int i = 0; i < 8; ++i){ int idx = base + i; if (idx < total) counts[idx] = run; run += v[i]; }
}

__global__ void k_s2(int* __restrict__ partials, int nb, int* __restrict__ bstart, int NBK){
  int lane = threadIdx.x;
  int orig = (lane < nb) ? partials[lane] : 0;
  int v = orig;
  for (int off = 1; off < 64; off <<= 1){
    int u = __shfl_up(v, off);
    if (lane >= off) v += u;
  }
  if (lane < nb) partials[lane] = v - orig;
  if (lane == nb - 1) bstart[NBK] = v;
}

__global__ __launch_bounds__(256) void k_s3(int* __restrict__ counts, int total,
                                            const int* __restrict__ partials, int B,
                                            int* __restrict__ bstart){
  int i = blockIdx.x * 256 + threadIdx.x;
  if (i >= total) return;
  int v = counts[i] + partials[i / 2048];
  counts[i] = v;
  if (i % B == 0) bstart[i / B] = v;
}

__global__ __launch_bounds__(256) void k_bscat(const int* __restrict__ ei, int E, int n,
                                               const int* __restrict__ counts, int B,
                                               int2* __restrict__ pairs, int NBK){
  __shared__ int cur[512];
  int t = threadIdx.x;
  for (int i = t; i < NBK; i += 256) cur[i] = counts[i * B + blockIdx.x];
  __syncthreads();
  int base = blockIdx.x * 8192;
  int end = base + 8192; if (end > E) end = E;
  for (int e = base + t; e < end; e += 256){
    int s = ei[e], d = ei[E + e];
    if ((unsigned)d >= (unsigned)n || (unsigned)s >= (unsigned)n) continue;
    int r = atomicAdd(&cur[d >> 8], 1);
    pairs[r] = make_int2(s, d);
  }
}

__global__ __launch_bounds__(256) void k_bucket(const int2* __restrict__ pairs, const int* __restrict__ bstart,
                                                int n, int* __restrict__ deg, int* __restrict__ excl,
                                                int* __restrict__ col){
  __shared__ int hist[256];
  __shared__ int sums[256];
  int t = threadIdx.x;
  int b = blockIdx.x;
  int S = bstart[b], T = bstart[b + 1];
  int base = b << 8;
  hist[t] = 0;
  __syncthreads();
  for (int e = S + t; e < T; e += 256)
    atomicAdd(&hist[pairs[e].y - base], 1);
  __syncthreads();
  int v = hist[t];
  sums[t] = v;
  __syncthreads();
  for (int off = 1; off < 256; off <<= 1){
    int add = (t >= off) ? sums[t - off] : 0;
    __syncthreads();
    sums[t] += add;
    __syncthreads();
  }
  int loc = sums[t] - v;
  int node = base + t;
  if (node < n){ deg[node] = v; excl[node] = S + loc; }
  __syncthreads();
  hist[t] = loc;
  __syncthreads();
  for (int e = S + t; e < T; e += 256){
    int2 pr = pairs[e];
    int r = atomicAdd(&hist[pr.y - base], 1);
    col[S + r] = pr.x;
  }
}

// ---------------- GEMM1 (MFMA bf16 -> fp8 rows + fused att1) ----------------
__global__ __launch_bounds__(256) void k_gemm1(const float* __restrict__ x, const float* __restrict__ W1,
                                               const float* __restrict__ asw, const float* __restrict__ adw,
                                               unsigned char* __restrict__ hq,
                                               float* __restrict__ a_s1, float* __restrict__ a_d1, int n){
  __shared__ __align__(16) char smem[45056];
  unsigned short (*As)[40]  = (unsigned short(*)[40])smem;
  unsigned short (*Bs)[136] = (unsigned short(*)[136])(smem + 10240);
  unsigned short (*T)[136]  = (unsigned short(*)[136])smem;
  int t = threadIdx.x;
  int l = t & 63, wid = t >> 6;
  int wm = wid >> 1, wn = wid & 1;
  int node0 = (int)blockIdx.x * 128;
  {
    int k = t >> 1;
    int ch = (t & 1) * 64;
    const float4* wr = (const float4*)(W1 + (size_t)k * 128 + ch);
    #pragma unroll
    for (int u = 0; u < 16; ++u){
      float4 f = wr[u];
      int c = ch + u * 4;
      Bs[c + 0][k] = f2bf(f.x);
      Bs[c + 1][k] = f2bf(f.y);
      Bs[c + 2][k] = f2bf(f.z);
      Bs[c + 3][k] = f2bf(f.w);
    }
  }
  f32x4 acc[4][4];
  #pragma unroll
  for (int i = 0; i < 4; ++i)
    #pragma unroll
    for (int j = 0; j < 4; ++j) acc[i][j] = (f32x4){0.f, 0.f, 0.f, 0.f};

  int lrow = l & 15, lk8 = (l >> 4) * 8;
  for (int kc = 0; kc < 4; ++kc){
    __syncthreads();
    {
      int row = t >> 1, kh = t & 1;
      int gn = node0 + row;
      const float4* src = (const float4*)(x + (size_t)gn * 128 + kc * 32 + kh * 16);
      float4 z = make_float4(0.f, 0.f, 0.f, 0.f);
      float4 f0 = (gn < n) ? src[0] : z;
      float4 f1 = (gn < n) ? src[1] : z;
      float4 f2 = (gn < n) ? src[2] : z;
      float4 f3 = (gn < n) ? src[3] : z;
      uint4 p0, p1;
      p0.x = pack2(f0.x, f0.y); p0.y = pack2(f0.z, f0.w);
      p0.z = pack2(f1.x, f1.y); p0.w = pack2(f1.z, f1.w);
      p1.x = pack2(f2.x, f2.y); p1.y = pack2(f2.z, f2.w);
      p1.z = pack2(f3.x, f3.y); p1.w = pack2(f3.z, f3.w);
      *(uint4*)&As[row][kh * 16]     = p0;
      *(uint4*)&As[row][kh * 16 + 8] = p1;
    }
    __syncthreads();
    bf16x8 a[4], b[4];
    #pragma unroll
    for (int mi = 0; mi < 4; ++mi)
      a[mi] = *(const bf16x8*)&As[wm * 64 + mi * 16 + lrow][lk8];
    #pragma unroll
    for (int ni = 0; ni < 4; ++ni)
      b[ni] = *(const bf16x8*)&Bs[wn * 64 + ni * 16 + lrow][kc * 32 + lk8];
    #pragma unroll
    for (int mi = 0; mi < 4; ++mi)
      #pragma unroll
      for (int ni = 0; ni < 4; ++ni)
        acc[mi][ni] = __builtin_amdgcn_mfma_f32_16x16x32_bf16(a[mi], b[ni], acc[mi][ni], 0, 0, 0);
  }
  __syncthreads();
  int rg = (l >> 4) * 4;
  #pragma unroll
  for (int mi = 0; mi < 4; ++mi)
    #pragma unroll
    for (int j = 0; j < 4; ++j){
      int nl = wm * 64 + mi * 16 + rg + j;
      #pragma unroll
      for (int ni = 0; ni < 4; ++ni)
        T[nl][wn * 64 + ni * 16 + lrow] = f2bf(acc[mi][ni][j]);
    }
  __syncthreads();
  {
    int r = t >> 1, half = t & 1;
    int gn = node0 + r;
    float ssv[4], ddv[4];
    #pragma unroll
    for (int c = 0; c < 4; ++c){
      int h = half * 4 + c;
      uint4 q0 = *(const uint4*)&T[r][half * 64 + c * 16];
      uint4 q1 = *(const uint4*)&T[r][half * 64 + c * 16 + 8];
      unsigned wv[8] = {q0.x, q0.y, q0.z, q0.w, q1.x, q1.y, q1.z, q1.w};
      float f[16];
      #pragma unroll
      for (int u = 0; u < 8; ++u){ f[2 * u] = lof(wv[u]); f[2 * u + 1] = hif(wv[u]); }
      float ss = 0.f, dd = 0.f;
      #pragma unroll
      for (int u = 0; u < 16; ++u){
        ss = fmaf(f[u], asw[h * 16 + u], ss);
        dd = fmaf(f[u], adw[h * 16 + u], dd);
      }
      ssv[c] = ss; ddv[c] = dd;
      uint4 pk;
      pk.x = (unsigned)__builtin_amdgcn_cvt_pk_fp8_f32(f[0],  f[1],  0, 0);
      pk.x = (unsigned)__builtin_amdgcn_cvt_pk_fp8_f32(f[2],  f[3],  (int)pk.x, 1);
      pk.y = (unsigned)__builtin_amdgcn_cvt_pk_fp8_f32(f[4],  f[5],  0, 0);
      pk.y = (unsigned)__builtin_amdgcn_cvt_pk_fp8_f32(f[6],  f[7],  (int)pk.y, 1);
      pk.z = (unsigned)__builtin_amdgcn_cvt_pk_fp8_f32(f[8],  f[9],  0, 0);
      pk.z = (unsigned)__builtin_amdgcn_cvt_pk_fp8_f32(f[10], f[11], (int)pk.z, 1);
      pk.w = (unsigned)__builtin_amdgcn_cvt_pk_fp8_f32(f[12], f[13], 0, 0);
      pk.w = (unsigned)__builtin_amdgcn_cvt_pk_fp8_f32(f[14], f[15], (int)pk.w, 1);
      if (gn < n) *(uint4*)(hq + (size_t)gn * 128 + half * 64 + c * 16) = pk;
    }
    if (gn < n){
      *(float4*)(a_s1 + (size_t)gn * 8 + half * 4) = make_float4(ssv[0], ssv[1], ssv[2], ssv[3]);
      *(float4*)(a_d1 + (size_t)gn * 8 + half * 4) = make_float4(ddv[0], ddv[1], ddv[2], ddv[3]);
    }
  }
}

// ---------------- agg1: fp8 rows, 8 edge-groups of 8 lanes (uint4 = 16 ch = 1 head/lane) ----------------
__global__ __launch_bounds__(256) void k_agg1(const unsigned char* __restrict__ hq, const float* __restrict__ a_s,
    const float* __restrict__ a_d, const int* __restrict__ col,
    const int* __restrict__ excl, const int* __restrict__ deg,
    const float* __restrict__ b1, unsigned short* __restrict__ out1b, int n){
  int tl = threadIdx.x & 63;
  int node = blockIdx.x * 4 + (threadIdx.x >> 6);
  if (node >= n) return;
  int g  = tl >> 3;          // edge group 0..7
  int il = tl & 7;           // head; channels [16il, 16il+16)
  float adn = a_d[(size_t)node * 8 + il];
  float ac[16];
  #pragma unroll
  for (int j = 0; j < 16; ++j) ac[j] = 0.f;
  float denom = 0.f;
  if (g == 0){
    float wSelf = lrelu_exp(a_s[(size_t)node * 8 + il] + adn);
    uint4 hv = *(const uint4*)(hq + (size_t)node * 128 + il * 16);
    unsigned q[4] = {hv.x, hv.y, hv.z, hv.w};
    #pragma unroll
    for (int j = 0; j < 4; ++j){
      f32x2 lo = __builtin_amdgcn_cvt_pk_f32_fp8((int)q[j], false);
      f32x2 hi = __builtin_amdgcn_cvt_pk_f32_fp8((int)q[j], true);
      ac[4*j]   = wSelf * lo[0]; ac[4*j+1] = wSelf * lo[1];
      ac[4*j+2] = wSelf * hi[0]; ac[4*j+3] = wSelf * hi[1];
    }
    denom = wSelf;
  }
  int pp = excl[node];
  int end = pp + deg[node];
  for (; pp + 16 <= end; pp += 16){
    int s[2]; float as[2]; uint4 v[2];
    #pragma unroll
    for (int u = 0; u < 2; ++u) s[u] = col[pp + 8 * u + g];
    #pragma unroll
    for (int u = 0; u < 2; ++u) as[u] = a_s[(size_t)s[u] * 8 + il];
    #pragma unroll
    for (int u = 0; u < 2; ++u) v[u] = *(const uint4*)(hq + (size_t)s[u] * 128 + il * 16);
    #pragma unroll
    for (int u = 0; u < 2; ++u){
      float w = lrelu_exp(as[u] + adn);
      unsigned q[4] = {v[u].x, v[u].y, v[u].z, v[u].w};
      #pragma unroll
      for (int j = 0; j < 4; ++j){
        f32x2 lo = __builtin_amdgcn_cvt_pk_f32_fp8((int)q[j], false);
        f32x2 hi = __builtin_amdgcn_cvt_pk_f32_fp8((int)q[j], true);
        ac[4*j]   = fmaf(w, lo[0], ac[4*j]);
        ac[4*j+1] = fmaf(w, lo[1], ac[4*j+1]);
        ac[4*j+2] = fmaf(w, hi[0], ac[4*j+2]);
        ac[4*j+3] = fmaf(w, hi[1], ac[4*j+3]);
      }
      denom += w;
    }
  }
  for (; pp + 8 <= end; pp += 8){
    int s0 = col[pp + g];
    float w = lrelu_exp(a_s[(size_t)s0 * 8 + il] + adn);
    uint4 v0 = *(const uint4*)(hq + (size_t)s0 * 128 + il * 16);
    unsigned q[4] = {v0.x, v0.y, v0.z, v0.w};
    #pragma unroll
    for (int j = 0; j < 4; ++j){
      f32x2 lo = __builtin_amdgcn_cvt_pk_f32_fp8((int)q[j], false);
      f32x2 hi = __builtin_amdgcn_cvt_pk_f32_fp8((int)q[j], true);
      ac[4*j]   = fmaf(w, lo[0], ac[4*j]);
      ac[4*j+1] = fmaf(w, lo[1], ac[4*j+1]);
      ac[4*j+2] = fmaf(w, hi[0], ac[4*j+2]);
      ac[4*j+3] = fmaf(w, hi[1], ac[4*j+3]);
    }
    denom += w;
  }
  if (pp + g < end){
    int s0 = col[pp + g];
    float w = lrelu_exp(a_s[(size_t)s0 * 8 + il] + adn);
    uint4 v0 = *(const uint4*)(hq + (size_t)s0 * 128 + il * 16);
    unsigned q[4] = {v0.x, v0.y, v0.z, v0.w};
    #pragma unroll
    for (int j = 0; j < 4; ++j){
      f32x2 lo = __builtin_amdgcn_cvt_pk_f32_fp8((int)q[j], false);
      f32x2 hi = __builtin_amdgcn_cvt_pk_f32_fp8((int)q[j], true);
      ac[4*j]   = fmaf(w, lo[0], ac[4*j]);
      ac[4*j+1] = fmaf(w, lo[1], ac[4*j+1]);
      ac[4*j+2] = fmaf(w, hi[0], ac[4*j+2]);
      ac[4*j+3] = fmaf(w, hi[1], ac[4*j+3]);
    }
    denom += w;
  }
  #pragma unroll
  for (int off = 8; off <= 32; off <<= 1){
    #pragma unroll
    for (int j = 0; j < 16; ++j) ac[j] += __shfl_xor(ac[j], off);
    denom += __shfl_xor(denom, off);
  }
  if (g == 0){
    float inv = 1.0f / denom;
    unsigned pk[8];
    #pragma unroll
    for (int j = 0; j < 8; ++j){
      float2 bb = *(const float2*)(b1 + il * 16 + j * 2);
      float o0 = fmaf(ac[2*j],   inv, bb.x); o0 = o0 > 0.f ? o0 : 0.f;
      float o1 = fmaf(ac[2*j+1], inv, bb.y); o1 = o1 > 0.f ? o1 : 0.f;
      pk[j] = pack2(o0, o1);
    }
    uint4* dst = (uint4*)(out1b + (size_t)node * 128 + il * 16);
    dst[0] = make_uint4(pk[0], pk[1], pk[2], pk[3]);
    dst[1] = make_uint4(pk[4], pk[5], pk[6], pk[7]);
  }
}

// ---------------- gemm2 + fused att2 -> fp8 rows [N][64B] with a_s embedded at byte 40 ----------------
__global__ __launch_bounds__(256) void k_gemm2a(const unsigned short* __restrict__ ab, const float* __restrict__ W2,
                                                const float* __restrict__ asw2, const float* __restrict__ adw2,
                                                unsigned char* __restrict__ h2q,
                                                float* __restrict__ a_d, int n){
  __shared__ unsigned short xs[32][256];
  __shared__ float ws[128][40];
  __shared__ float ssb[256], ddb[256];
  int t = threadIdx.x;
  for (int i = t; i < 128 * 40; i += 256) (&ws[0][0])[i] = W2[i];
  ssb[t] = 0.f; ddb[t] = 0.f;
  int ng = t & 63, cg = t >> 6;
  int node0 = blockIdx.x * 256;
  float acc[4][10];
  #pragma unroll
  for (int i = 0; i < 4; ++i)
    #pragma unroll
    for (int j = 0; j < 10; ++j) acc[i][j] = 0.0f;

  for (int kc = 0; kc < 4; ++kc){
    int k0 = kc * 32;
    __syncthreads();
    {
      int gn = node0 + t;
      uint4 q0, q1, r0, r1;
      uint4 z = make_uint4(0, 0, 0, 0);
      if (gn < n){
        const uint4* src = (const uint4*)(ab + (size_t)gn * 128 + k0);
        q0 = src[0]; q1 = src[1]; r0 = src[2]; r1 = src[3];
      } else { q0 = z; q1 = z; r0 = z; r1 = z; }
      unsigned w16[8] = {q0.x, q0.y, q0.z, q0.w, q1.x, q1.y, q1.z, q1.w};
      #pragma unroll
      for (int j = 0; j < 8; ++j){
        xs[j * 2][t]     = (unsigned short)(w16[j] & 0xffffu);
        xs[j * 2 + 1][t] = (unsigned short)(w16[j] >> 16);
      }
      unsigned w16b[8] = {r0.x, r0.y, r0.z, r0.w, r1.x, r1.y, r1.z, r1.w};
      #pragma unroll
      for (int j = 0; j < 8; ++j){
        xs[16 + j * 2][t]     = (unsigned short)(w16b[j] & 0xffffu);
        xs[16 + j * 2 + 1][t] = (unsigned short)(w16b[j] >> 16);
      }
    }
    __syncthreads();
    #pragma unroll 4
    for (int k = 0; k < 32; ++k){
      float xv[4];
      #pragma unroll
      for (int i = 0; i < 4; ++i) xv[i] = __uint_as_float(((unsigned)xs[k][ng + 64 * i]) << 16);
      float wv[10];
      #pragma unroll
      for (int j = 0; j < 10; ++j) wv[j] = ws[k0 + k][cg * 10 + j];
      #pragma unroll
      for (int i = 0; i < 4; ++i)
        #pragma unroll
        for (int j = 0; j < 10; ++j) acc[i][j] = fmaf(xv[i], wv[j], acc[i][j]);
    }
  }
  float asl[10], adl[10];
  #pragma unroll
  for (int j = 0; j < 10; ++j){ asl[j] = asw2[cg * 10 + j]; adl[j] = adw2[cg * 10 + j]; }
  #pragma unroll
  for (int i = 0; i < 4; ++i){
    float ssi = 0.f, ddi = 0.f;
    #pragma unroll
    for (int j = 0; j < 10; ++j){
      ssi = fmaf(acc[i][j], asl[j], ssi);
      ddi = fmaf(acc[i][j], adl[j], ddi);
    }
    atomicAdd(&ssb[ng + 64 * i], ssi);
    atomicAdd(&ddb[ng + 64 * i], ddi);
  }
  __syncthreads();
  unsigned char* RB = (unsigned char*)xs;
  #pragma unroll
  for (int i = 0; i < 4; ++i){
    int row = ng + 64 * i;
    unsigned char* dst = &RB[row * 64 + cg * 10];
    #pragma unroll
    for (int j = 0; j < 10; j += 2){
      int p2 = __builtin_amdgcn_cvt_pk_fp8_f32(acc[i][j], acc[i][j + 1], 0, 0);
      dst[j]     = (unsigned char)(p2 & 0xff);
      dst[j + 1] = (unsigned char)((p2 >> 8) & 0xff);
    }
  }
  *(float*)&RB[t * 64 + 40] = ssb[t];
  __syncthreads();
  {
    int gn = node0 + t;
    if (gn < n){
      a_d[gn] = ddb[t];
      uint4* drow = (uint4*)(h2q + (size_t)gn * 64);
      const uint4* srow = (const uint4*)&RB[t * 64];
      drow[0] = srow[0]; drow[1] = srow[1]; drow[2] = srow[2]; drow[3] = srow[3];
    }
  }
}

// ---------------- agg2 + log_softmax: 64B fp8 rows, 8 edge-groups of 8 lanes ----------------
__global__ __launch_bounds__(256) void k_agg2(const unsigned char* __restrict__ h2q,
    const float* __restrict__ a_d, const int* __restrict__ col,
    const int* __restrict__ excl, const int* __restrict__ deg,
    const float* __restrict__ b2, float* __restrict__ out, int n){
  int tl = threadIdx.x & 63;
  int node = blockIdx.x * 4 + (threadIdx.x >> 6);
  if (node >= n) return;
  int g = tl >> 3, il = tl & 7;
  bool act = il < 5;                       // channels 8il..8il+7 (< 40)
  float adn = a_d[node];
  float ac[8];
  #pragma unroll
  for (int j = 0; j < 8; ++j) ac[j] = 0.f;
  float denom = 0.f;
  if (g == 0){
    uint2 hv = *(const uint2*)(h2q + (size_t)node * 64 + il * 8);
    float asf = __uint_as_float(__shfl(hv.x, 5));
    float wSelf = lrelu_exp(asf + adn);
    uint2 mv = act ? hv : make_uint2(0u, 0u);
    f32x2 l0 = __builtin_amdgcn_cvt_pk_f32_fp8((int)mv.x, false);
    f32x2 h0 = __builtin_amdgcn_cvt_pk_f32_fp8((int)mv.x, true);
    f32x2 l1 = __builtin_amdgcn_cvt_pk_f32_fp8((int)mv.y, false);
    f32x2 h1 = __builtin_amdgcn_cvt_pk_f32_fp8((int)mv.y, true);
    ac[0] = wSelf * l0[0]; ac[1] = wSelf * l0[1]; ac[2] = wSelf * h0[0]; ac[3] = wSelf * h0[1];
    ac[4] = wSelf * l1[0]; ac[5] = wSelf * l1[1]; ac[6] = wSelf * h1[0]; ac[7] = wSelf * h1[1];
    denom = wSelf;
  }
  int pp = excl[node];
  int end = pp + deg[node];
  for (; pp + 16 <= end; pp += 16){
    int s[2]; uint2 v[2];
    #pragma unroll
    for (int u = 0; u < 2; ++u) s[u] = col[pp + 8 * u + g];
    #pragma unroll
    for (int u = 0; u < 2; ++u) v[u] = *(const uint2*)(h2q + (size_t)s[u] * 64 + il * 8);
    #pragma unroll
    for (int u = 0; u < 2; ++u){
      float asf = __uint_as_float(__shfl(v[u].x, (g << 3) + 5));
      float w = lrelu_exp(asf + adn);
      uint2 mv = act ? v[u] : make_uint2(0u, 0u);
      f32x2 l0 = __builtin_amdgcn_cvt_pk_f32_fp8((int)mv.x, false);
      f32x2 h0 = __builtin_amdgcn_cvt_pk_f32_fp8((int)mv.x, true);
      f32x2 l1 = __builtin_amdgcn_cvt_pk_f32_fp8((int)mv.y, false);
      f32x2 h1 = __builtin_amdgcn_cvt_pk_f32_fp8((int)mv.y, true);
      ac[0] = fmaf(w, l0[0], ac[0]); ac[1] = fmaf(w, l0[1], ac[1]);
      ac[2] = fmaf(w, h0[0], ac[2]); ac[3] = fmaf(w, h0[1], ac[3]);
      ac[4] = fmaf(w, l1[0], ac[4]); ac[5] = fmaf(w, l1[1], ac[5]);
      ac[6] = fmaf(w, h1[0], ac[6]); ac[7] = fmaf(w, h1[1], ac[7]);
      denom += w;
    }
  }
  for (; pp + 8 <= end; pp += 8){
    int s0 = col[pp + g];
    uint2 v0 = *(const uint2*)(h2q + (size_t)s0 * 64 + il * 8);
    float asf = __uint_as_float(__shfl(v0.x, (g << 3) + 5));
    float w = lrelu_exp(asf + adn);
    uint2 mv = act ? v0 : make_uint2(0u, 0u);
    f32x2 l0 = __builtin_amdgcn_cvt_pk_f32_fp8((int)mv.x, false);
    f32x2 h0 = __builtin_amdgcn_cvt_pk_f32_fp8((int)mv.x, true);
    f32x2 l1 = __builtin_amdgcn_cvt_pk_f32_fp8((int)mv.y, false);
    f32x2 h1 = __builtin_amdgcn_cvt_pk_f32_fp8((int)mv.y, true);
    ac[0] = fmaf(w, l0[0], ac[0]); ac[1] = fmaf(w, l0[1], ac[1]);
    ac[2] = fmaf(w, h0[0], ac[2]); ac[3] = fmaf(w, h0[1], ac[3]);
    ac[4] = fmaf(w, l1[0], ac[4]); ac[5] = fmaf(w, l1[1], ac[5]);
    ac[6] = fmaf(w, h1[0], ac[6]); ac[7] = fmaf(w, h1[1], ac[7]);
    denom += w;
  }
  if (pp + g < end){
    int s0 = col[pp + g];
    uint2 v0 = *(const uint2*)(h2q + (size_t)s0 * 64 + il * 8);
    float asf = __uint_as_float(__shfl(v0.x, (g << 3) + 5));
    float w = lrelu_exp(asf + adn);
    uint2 mv = act ? v0 : make_uint2(0u, 0u);
    f32x2 l0 = __builtin_amdgcn_cvt_pk_f32_fp8((int)mv.x, false);
    f32x2 h0 = __builtin_amdgcn_cvt_pk_f32_fp8((int)mv.x, true);
    f32x2 l1 = __builtin_amdgcn_cvt_pk_f32_fp8((int)mv.y, false);
    f32x2 h1 = __builtin_amdgcn_cvt_pk_f32_fp8((int)mv.y, true);
    ac[0] = fmaf(w, l0[0], ac[0]); ac[1] = fmaf(w, l0[1], ac[1]);
    ac[2] = fmaf(w, h0[0], ac[2]); ac[3] = fmaf(w, h0[1], ac[3]);
    ac[4] = fmaf(w, l1[0], ac[4]); ac[5] = fmaf(w, l1[1], ac[5]);
    ac[6] = fmaf(w, h1[0], ac[6]); ac[7] = fmaf(w, h1[1], ac[7]);
    denom += w;
  }
  #pragma unroll
  for (int off = 8; off <= 32; off <<= 1){
    #pragma unroll
    for (int j = 0; j < 8; ++j) ac[j] += __shfl_xor(ac[j], off);
    denom += __shfl_xor(denom, off);
  }
  float inv = 1.0f / denom;
  float vv[8];
  #pragma unroll
  for (int j = 0; j < 8; ++j){
    float bbj = act ? b2[il * 8 + j] : 0.f;
    vv[j] = act ? fmaf(ac[j], inv, bbj) : -1e30f;
  }
  float m = vv[0];
  #pragma unroll
  for (int j = 1; j < 8; ++j) m = fmaxf(m, vv[j]);
  #pragma unroll
  for (int off = 4; off >= 1; off >>= 1) m = fmaxf(m, __shfl_xor(m, off));
  float S = 0.f;
  if (act){
    #pragma unroll
    for (int j = 0; j < 8; ++j) S += __expf(vv[j] - m);
  }
  #pragma unroll
  for (int off = 4; off >= 1; off >>= 1) S += __shfl_xor(S, off);
  float ls = __logf(S);
  if (act && g == 0){
    float4 o0 = make_float4(vv[0] - m - ls, vv[1] - m - ls, vv[2] - m - ls, vv[3] - m - ls);
    float4 o1 = make_float4(vv[4] - m - ls, vv[5] - m - ls, vv[6] - m - ls, vv[7] - m - ls);
    *(float4*)(out + (size_t)node * 40 + il * 8)     = o0;
    *(float4*)(out + (size_t)node * 40 + il * 8 + 4) = o1;
  }
}

extern "C" void kernel_launch(void* const* d_in, const int* in_sizes, int n_in,
                              void* d_out, int out_size, void* d_ws, size_t ws_size,
                              hipStream_t stream){
  const float* x    = (const float*)d_in[0];
  const int*   ei   = (const int*)d_in[1];          // int32 (jax x64 disabled)
  const float* W1   = (const float*)d_in[2];
  const float* as1w = (const float*)d_in[3];
  const float* ad1w = (const float*)d_in[4];
  const float* b1   = (const float*)d_in[5];
  const float* W2   = (const float*)d_in[6];
  const float* as2w = (const float*)d_in[7];
  const float* ad2w = (const float*)d_in[8];
  const float* b2   = (const float*)d_in[9];
  float* out = (float*)d_out;
  const int N = in_sizes[0] / 128;
  const int E = in_sizes[1] / 2;

  const int NBK = (N + 255) / 256;
  const int B   = (E + 8191) / 8192;
  const int total = NBK * B;
  const int nsc = (total + 2047) / 2048;

  char* p = (char*)d_ws;
  auto alloc = [&](size_t bytes) -> void* {
    void* r = (void*)p;
    p += (bytes + 511) & ~(size_t)511;
    return r;
  };
  int*            deg      = (int*)           alloc((size_t)N * 4);
  int*            excl     = (int*)           alloc((size_t)N * 4);
  int*            counts   = (int*)           alloc((size_t)total * 4);
  int*            bstart   = (int*)           alloc((size_t)(NBK + 1) * 4);
  int*            partials = (int*)           alloc(64 * 4);
  int2*           pairs    = (int2*)          alloc((size_t)E * 8);
  int*            col      = (int*)           alloc((size_t)E * 4);
  float*          a_s1     = (float*)         alloc((size_t)N * 8 * 4);
  float*          a_d1     = (float*)         alloc((size_t)N * 8 * 4);
  unsigned short* out1b    = (unsigned short*)alloc((size_t)N * 128 * 2);
  unsigned char*  h1q      = (unsigned char*) alloc((size_t)N * 128);
  unsigned char*  h2q  = h1q;
  float*          a_d2 = (float*)(h1q + (size_t)N * 64 + 256);

  int nG1 = (N + 127) / 128;

  k_gemm1 <<<nG1, 256, 0, stream>>>(x, W1, as1w, ad1w, h1q, a_s1, a_d1, N);
  k_cnt   <<<B, 256, 0, stream>>>(ei, E, N, counts, B, NBK);
  k_s1    <<<nsc, 256, 0, stream>>>(counts, total, partials);
  k_s2    <<<1, 64, 0, stream>>>(partials, nsc, bstart, NBK);
  k_s3    <<<(total + 255) / 256, 256, 0, stream>>>(counts, total, partials, B, bstart);
  k_bscat <<<B, 256, 0, stream>>>(ei, E, N, counts, B, pairs, NBK);
  k_bucket<<<NBK, 256, 0, stream>>>(pairs, bstart, N, deg, excl, col);
  k_agg1  <<<(N + 3) / 4, 256, 0, stream>>>(h1q, a_s1, a_d1, col, excl, deg, b1, out1b, N);
  k_gemm2a<<<(N + 255) / 256, 256, 0, stream>>>(out1b, W2, as2w, ad2w, h2q, a_d2, N);
  k_agg2  <<<(N + 3) / 4, 256, 0, stream>>>(h2q, a_d2, col, excl, deg, b2, out, N);
}

// Round 19
// 253.789 us; speedup vs baseline: 1.0819x; 1.0819x over previous
//
#include <hip/hip_runtime.h>
#include <hip/hip_bf16.h>
#include <cstdint>

#define TB 256

typedef __attribute__((ext_vector_type(8))) short bf16x8;
typedef __attribute__((ext_vector_type(4))) float f32x4;
typedef __attribute__((ext_vector_type(2))) float f32x2;

__device__ __forceinline__ float lrelu_exp(float e){
  e = e > 0.0f ? e : 0.2f * e;
  return __expf(e);
}
__device__ __forceinline__ unsigned short f2bf(float f){
  unsigned u = __float_as_uint(f);
  u = (u + 0x7fffu + ((u >> 16) & 1u)) >> 16;   // RNE
  return (unsigned short)u;
}
__device__ __forceinline__ float lof(unsigned u){ return __uint_as_float(u << 16); }
__device__ __forceinline__ float hif(unsigned u){ return __uint_as_float(u & 0xffff0000u); }
__device__ __forceinline__ unsigned pack2(float a, float b){
  return (unsigned)f2bf(a) | ((unsigned)f2bf(b) << 16);
}

// ================= CSR build via 2-level bucket sort (LDS atomics only) =================

__global__ __launch_bounds__(256) void k_cnt(const int* __restrict__ ei, int E, int n,
                                             int* __restrict__ counts, int B, int NBK){
  __shared__ int h[512];
  int t = threadIdx.x;
  for (int i = t; i < NBK; i += 256) h[i] = 0;
  __syncthreads();
  int base = blockIdx.x * 8192;
  int end = base + 8192; if (end > E) end = E;
  for (int e = base + t; e < end; e += 256){
    int d = ei[E + e];
    if ((unsigned)d < (unsigned)n) atomicAdd(&h[d >> 8], 1);
  }
  __syncthreads();
  for (int i = t; i < NBK; i += 256) counts[i * B + blockIdx.x] = h[i];
}

__global__ __launch_bounds__(256) void k_s1(int* __restrict__ counts, int total, int* __restrict__ partials){
  __shared__ int sums[256];
  int t = threadIdx.x;
  int base = blockIdx.x * 2048 + t * 8;
  int v[8]; int s = 0;
  #pragma unroll
  for (int i = 0; i < 8; ++i){ int idx = base + i; v[i] = (idx < total) ? counts[idx] : 0; s += v[i]; }
  sums[t] = s;
  __syncthreads();
  for (int off = 1; off < 256; off <<= 1){
    int add = (t >= off) ? sums[t - off] : 0;
    __syncthreads();
    sums[t] += add;
    __syncthreads();
  }
  int run = sums[t] - s;
  if (t == 255) partials[blockIdx.x] = sums[t];
  #pragma unroll
  for (int i = 0; i < 8; ++i){ int idx = base + i; if (idx < total) counts[idx] = run; run += v[i]; }
}

__global__ void k_s2(int* __restrict__ partials, int nb, int* __restrict__ bstart, int NBK){
  int lane = threadIdx.x;
  int orig = (lane < nb) ? partials[lane] : 0;
  int v = orig;
  for (int off = 1; off < 64; off <<= 1){
    int u = __shfl_up(v, off);
    if (lane >= off) v += u;
  }
  if (lane < nb) partials[lane] = v - orig;
  if (lane == nb - 1) bstart[NBK] = v;
}

__global__ __launch_bounds__(256) void k_s3(int* __restrict__ counts, int total,
                                            const int* __restrict__ partials, int B,
                                            int* __restrict__ bstart){
  int i = blockIdx.x * 256 + threadIdx.x;
  if (i >= total) return;
  int v = counts[i] + partials[i / 2048];
  counts[i] = v;
  if (i % B == 0) bstart[i / B] = v;
}

__global__ __launch_bounds__(256) void k_bscat(const int* __restrict__ ei, int E, int n,
                                               const int* __restrict__ counts, int B,
                                               int2* __restrict__ pairs, int NBK){
  __shared__ int cur[512];
  int t = threadIdx.x;
  for (int i = t; i < NBK; i += 256) cur[i] = counts[i * B + blockIdx.x];
  __syncthreads();
  int base = blockIdx.x * 8192;
  int end = base + 8192; if (end > E) end = E;
  for (int e = base + t; e < end; e += 256){
    int s = ei[e], d = ei[E + e];
    if ((unsigned)d >= (unsigned)n || (unsigned)s >= (unsigned)n) continue;
    int r = atomicAdd(&cur[d >> 8], 1);
    pairs[r] = make_int2(s, d);
  }
}

__global__ __launch_bounds__(256) void k_bucket(const int2* __restrict__ pairs, const int* __restrict__ bstart,
                                                int n, int* __restrict__ deg, int* __restrict__ excl,
                                                int* __restrict__ col){
  __shared__ int hist[256];
  __shared__ int sums[256];
  int t = threadIdx.x;
  int b = blockIdx.x;
  int S = bstart[b], T = bstart[b + 1];
  int base = b << 8;
  hist[t] = 0;
  __syncthreads();
  for (int e = S + t; e < T; e += 256)
    atomicAdd(&hist[pairs[e].y - base], 1);
  __syncthreads();
  int v = hist[t];
  sums[t] = v;
  __syncthreads();
  for (int off = 1; off < 256; off <<= 1){
    int add = (t >= off) ? sums[t - off] : 0;
    __syncthreads();
    sums[t] += add;
    __syncthreads();
  }
  int loc = sums[t] - v;
  int node = base + t;
  if (node < n){ deg[node] = v; excl[node] = S + loc; }
  __syncthreads();
  hist[t] = loc;
  __syncthreads();
  for (int e = S + t; e < T; e += 256){
    int2 pr = pairs[e];
    int r = atomicAdd(&hist[pr.y - base], 1);
    col[S + r] = pr.x;
  }
}

// ---------------- GEMM1 (MFMA bf16 -> fp8 rows + fused att1) ----------------
__global__ __launch_bounds__(256) void k_gemm1(const float* __restrict__ x, const float* __restrict__ W1,
                                               const float* __restrict__ asw, const float* __restrict__ adw,
                                               unsigned char* __restrict__ hq,
                                               float* __restrict__ a_s1, float* __restrict__ a_d1, int n){
  __shared__ __align__(16) char smem[45056];
  unsigned short (*As)[40]  = (unsigned short(*)[40])smem;
  unsigned short (*Bs)[136] = (unsigned short(*)[136])(smem + 10240);
  unsigned short (*T)[136]  = (unsigned short(*)[136])smem;
  int t = threadIdx.x;
  int l = t & 63, wid = t >> 6;
  int wm = wid >> 1, wn = wid & 1;
  int node0 = (int)blockIdx.x * 128;
  {
    int k = t >> 1;
    int ch = (t & 1) * 64;
    const float4* wr = (const float4*)(W1 + (size_t)k * 128 + ch);
    #pragma unroll
    for (int u = 0; u < 16; ++u){
      float4 f = wr[u];
      int c = ch + u * 4;
      Bs[c + 0][k] = f2bf(f.x);
      Bs[c + 1][k] = f2bf(f.y);
      Bs[c + 2][k] = f2bf(f.z);
      Bs[c + 3][k] = f2bf(f.w);
    }
  }
  f32x4 acc[4][4];
  #pragma unroll
  for (int i = 0; i < 4; ++i)
    #pragma unroll
    for (int j = 0; j < 4; ++j) acc[i][j] = (f32x4){0.f, 0.f, 0.f, 0.f};

  int lrow = l & 15, lk8 = (l >> 4) * 8;
  for (int kc = 0; kc < 4; ++kc){
    __syncthreads();
    {
      int row = t >> 1, kh = t & 1;
      int gn = node0 + row;
      const float4* src = (const float4*)(x + (size_t)gn * 128 + kc * 32 + kh * 16);
      float4 z = make_float4(0.f, 0.f, 0.f, 0.f);
      float4 f0 = (gn < n) ? src[0] : z;
      float4 f1 = (gn < n) ? src[1] : z;
      float4 f2 = (gn < n) ? src[2] : z;
      float4 f3 = (gn < n) ? src[3] : z;
      uint4 p0, p1;
      p0.x = pack2(f0.x, f0.y); p0.y = pack2(f0.z, f0.w);
      p0.z = pack2(f1.x, f1.y); p0.w = pack2(f1.z, f1.w);
      p1.x = pack2(f2.x, f2.y); p1.y = pack2(f2.z, f2.w);
      p1.z = pack2(f3.x, f3.y); p1.w = pack2(f3.z, f3.w);
      *(uint4*)&As[row][kh * 16]     = p0;
      *(uint4*)&As[row][kh * 16 + 8] = p1;
    }
    __syncthreads();
    bf16x8 a[4], b[4];
    #pragma unroll
    for (int mi = 0; mi < 4; ++mi)
      a[mi] = *(const bf16x8*)&As[wm * 64 + mi * 16 + lrow][lk8];
    #pragma unroll
    for (int ni = 0; ni < 4; ++ni)
      b[ni] = *(const bf16x8*)&Bs[wn * 64 + ni * 16 + lrow][kc * 32 + lk8];
    #pragma unroll
    for (int mi = 0; mi < 4; ++mi)
      #pragma unroll
      for (int ni = 0; ni < 4; ++ni)
        acc[mi][ni] = __builtin_amdgcn_mfma_f32_16x16x32_bf16(a[mi], b[ni], acc[mi][ni], 0, 0, 0);
  }
  __syncthreads();
  int rg = (l >> 4) * 4;
  #pragma unroll
  for (int mi = 0; mi < 4; ++mi)
    #pragma unroll
    for (int j = 0; j < 4; ++j){
      int nl = wm * 64 + mi * 16 + rg + j;
      #pragma unroll
      for (int ni = 0; ni < 4; ++ni)
        T[nl][wn * 64 + ni * 16 + lrow] = f2bf(acc[mi][ni][j]);
    }
  __syncthreads();
  {
    int r = t >> 1, half = t & 1;
    int gn = node0 + r;
    float ssv[4], ddv[4];
    #pragma unroll
    for (int c = 0; c < 4; ++c){
      int h = half * 4 + c;
      uint4 q0 = *(const uint4*)&T[r][half * 64 + c * 16];
      uint4 q1 = *(const uint4*)&T[r][half * 64 + c * 16 + 8];
      unsigned wv[8] = {q0.x, q0.y, q0.z, q0.w, q1.x, q1.y, q1.z, q1.w};
      float f[16];
      #pragma unroll
      for (int u = 0; u < 8; ++u){ f[2 * u] = lof(wv[u]); f[2 * u + 1] = hif(wv[u]); }
      float ss = 0.f, dd = 0.f;
      #pragma unroll
      for (int u = 0; u < 16; ++u){
        ss = fmaf(f[u], asw[h * 16 + u], ss);
        dd = fmaf(f[u], adw[h * 16 + u], dd);
      }
      ssv[c] = ss; ddv[c] = dd;
      uint4 pk;
      pk.x = (unsigned)__builtin_amdgcn_cvt_pk_fp8_f32(f[0],  f[1],  0, 0);
      pk.x = (unsigned)__builtin_amdgcn_cvt_pk_fp8_f32(f[2],  f[3],  (int)pk.x, 1);
      pk.y = (unsigned)__builtin_amdgcn_cvt_pk_fp8_f32(f[4],  f[5],  0, 0);
      pk.y = (unsigned)__builtin_amdgcn_cvt_pk_fp8_f32(f[6],  f[7],  (int)pk.y, 1);
      pk.z = (unsigned)__builtin_amdgcn_cvt_pk_fp8_f32(f[8],  f[9],  0, 0);
      pk.z = (unsigned)__builtin_amdgcn_cvt_pk_fp8_f32(f[10], f[11], (int)pk.z, 1);
      pk.w = (unsigned)__builtin_amdgcn_cvt_pk_fp8_f32(f[12], f[13], 0, 0);
      pk.w = (unsigned)__builtin_amdgcn_cvt_pk_fp8_f32(f[14], f[15], (int)pk.w, 1);
      if (gn < n) *(uint4*)(hq + (size_t)gn * 128 + half * 64 + c * 16) = pk;
    }
    if (gn < n){
      *(float4*)(a_s1 + (size_t)gn * 8 + half * 4) = make_float4(ssv[0], ssv[1], ssv[2], ssv[3]);
      *(float4*)(a_d1 + (size_t)gn * 8 + half * 4) = make_float4(ddv[0], ddv[1], ddv[2], ddv[3]);
    }
  }
}

// ---- agg1: 2 nodes/wave, 4 edge-groups x 8 lanes per node (head/lane, uint4 = 16 ch) ----
__global__ __launch_bounds__(256) void k_agg1(const unsigned char* __restrict__ hq, const float* __restrict__ a_s,
    const float* __restrict__ a_d, const int* __restrict__ col,
    const int* __restrict__ excl, const int* __restrict__ deg,
    const float* __restrict__ b1, unsigned short* __restrict__ out1b, int n){
  int tl = threadIdx.x & 63;
  int half = tl >> 5;
  int node = blockIdx.x * 8 + (threadIdx.x >> 6) * 2 + half;
  if (node >= n) return;
  int lt = tl & 31;
  int g  = lt >> 3;          // edge group 0..3 (within node)
  int il = lt & 7;           // head; channels [16il, 16il+16)
  float adn = a_d[(size_t)node * 8 + il];
  float ac[16];
  #pragma unroll
  for (int j = 0; j < 16; ++j) ac[j] = 0.f;
  float denom = 0.f;
  if (g == 0){
    float wSelf = lrelu_exp(a_s[(size_t)node * 8 + il] + adn);
    uint4 hv = *(const uint4*)(hq + (size_t)node * 128 + il * 16);
    unsigned q[4] = {hv.x, hv.y, hv.z, hv.w};
    #pragma unroll
    for (int j = 0; j < 4; ++j){
      f32x2 lo = __builtin_amdgcn_cvt_pk_f32_fp8((int)q[j], false);
      f32x2 hi = __builtin_amdgcn_cvt_pk_f32_fp8((int)q[j], true);
      ac[4*j]   = wSelf * lo[0]; ac[4*j+1] = wSelf * lo[1];
      ac[4*j+2] = wSelf * hi[0]; ac[4*j+3] = wSelf * hi[1];
    }
    denom = wSelf;
  }
  int pp = excl[node];
  int end = pp + deg[node];
  for (; pp + 16 <= end; pp += 16){
    int s[4]; float as[4]; uint4 v[4];
    #pragma unroll
    for (int u = 0; u < 4; ++u) s[u] = col[pp + 4 * u + g];
    #pragma unroll
    for (int u = 0; u < 4; ++u) as[u] = a_s[(size_t)s[u] * 8 + il];
    #pragma unroll
    for (int u = 0; u < 4; ++u) v[u] = *(const uint4*)(hq + (size_t)s[u] * 128 + il * 16);
    #pragma unroll
    for (int u = 0; u < 4; ++u){
      float w = lrelu_exp(as[u] + adn);
      unsigned q[4] = {v[u].x, v[u].y, v[u].z, v[u].w};
      #pragma unroll
      for (int j = 0; j < 4; ++j){
        f32x2 lo = __builtin_amdgcn_cvt_pk_f32_fp8((int)q[j], false);
        f32x2 hi = __builtin_amdgcn_cvt_pk_f32_fp8((int)q[j], true);
        ac[4*j]   = fmaf(w, lo[0], ac[4*j]);
        ac[4*j+1] = fmaf(w, lo[1], ac[4*j+1]);
        ac[4*j+2] = fmaf(w, hi[0], ac[4*j+2]);
        ac[4*j+3] = fmaf(w, hi[1], ac[4*j+3]);
      }
      denom += w;
    }
  }
  for (; pp + 4 <= end; pp += 4){
    int s0 = col[pp + g];
    float w = lrelu_exp(a_s[(size_t)s0 * 8 + il] + adn);
    uint4 v0 = *(const uint4*)(hq + (size_t)s0 * 128 + il * 16);
    unsigned q[4] = {v0.x, v0.y, v0.z, v0.w};
    #pragma unroll
    for (int j = 0; j < 4; ++j){
      f32x2 lo = __builtin_amdgcn_cvt_pk_f32_fp8((int)q[j], false);
      f32x2 hi = __builtin_amdgcn_cvt_pk_f32_fp8((int)q[j], true);
      ac[4*j]   = fmaf(w, lo[0], ac[4*j]);
      ac[4*j+1] = fmaf(w, lo[1], ac[4*j+1]);
      ac[4*j+2] = fmaf(w, hi[0], ac[4*j+2]);
      ac[4*j+3] = fmaf(w, hi[1], ac[4*j+3]);
    }
    denom += w;
  }
  if (pp + g < end){
    int s0 = col[pp + g];
    float w = lrelu_exp(a_s[(size_t)s0 * 8 + il] + adn);
    uint4 v0 = *(const uint4*)(hq + (size_t)s0 * 128 + il * 16);
    unsigned q[4] = {v0.x, v0.y, v0.z, v0.w};
    #pragma unroll
    for (int j = 0; j < 4; ++j){
      f32x2 lo = __builtin_amdgcn_cvt_pk_f32_fp8((int)q[j], false);
      f32x2 hi = __builtin_amdgcn_cvt_pk_f32_fp8((int)q[j], true);
      ac[4*j]   = fmaf(w, lo[0], ac[4*j]);
      ac[4*j+1] = fmaf(w, lo[1], ac[4*j+1]);
      ac[4*j+2] = fmaf(w, hi[0], ac[4*j+2]);
      ac[4*j+3] = fmaf(w, hi[1], ac[4*j+3]);
    }
    denom += w;
  }
  #pragma unroll
  for (int off = 8; off <= 16; off <<= 1){
    #pragma unroll
    for (int j = 0; j < 16; ++j) ac[j] += __shfl_xor(ac[j], off);
    denom += __shfl_xor(denom, off);
  }
  if (g == 0){
    float inv = 1.0f / denom;
    unsigned pk[8];
    #pragma unroll
    for (int j = 0; j < 8; ++j){
      float2 bb = *(const float2*)(b1 + il * 16 + j * 2);
      float o0 = fmaf(ac[2*j],   inv, bb.x); o0 = o0 > 0.f ? o0 : 0.f;
      float o1 = fmaf(ac[2*j+1], inv, bb.y); o1 = o1 > 0.f ? o1 : 0.f;
      pk[j] = pack2(o0, o1);
    }
    uint4* dst = (uint4*)(out1b + (size_t)node * 128 + il * 16);
    dst[0] = make_uint4(pk[0], pk[1], pk[2], pk[3]);
    dst[1] = make_uint4(pk[4], pk[5], pk[6], pk[7]);
  }
}

// ---------------- gemm2 + fused att2 -> fp8 rows [N][64B] with a_s embedded at byte 40 ----------------
__global__ __launch_bounds__(256) void k_gemm2a(const unsigned short* __restrict__ ab, const float* __restrict__ W2,
                                                const float* __restrict__ asw2, const float* __restrict__ adw2,
                                                unsigned char* __restrict__ h2q,
                                                float* __restrict__ a_d, int n){
  __shared__ unsigned short xs[32][256];
  __shared__ float ws[128][40];
  __shared__ float ssb[256], ddb[256];
  int t = threadIdx.x;
  for (int i = t; i < 128 * 40; i += 256) (&ws[0][0])[i] = W2[i];
  ssb[t] = 0.f; ddb[t] = 0.f;
  int ng = t & 63, cg = t >> 6;
  int node0 = blockIdx.x * 256;
  float acc[4][10];
  #pragma unroll
  for (int i = 0; i < 4; ++i)
    #pragma unroll
    for (int j = 0; j < 10; ++j) acc[i][j] = 0.0f;

  for (int kc = 0; kc < 4; ++kc){
    int k0 = kc * 32;
    __syncthreads();
    {
      int gn = node0 + t;
      uint4 q0, q1, r0, r1;
      uint4 z = make_uint4(0, 0, 0, 0);
      if (gn < n){
        const uint4* src = (const uint4*)(ab + (size_t)gn * 128 + k0);
        q0 = src[0]; q1 = src[1]; r0 = src[2]; r1 = src[3];
      } else { q0 = z; q1 = z; r0 = z; r1 = z; }
      unsigned w16[8] = {q0.x, q0.y, q0.z, q0.w, q1.x, q1.y, q1.z, q1.w};
      #pragma unroll
      for (int j = 0; j < 8; ++j){
        xs[j * 2][t]     = (unsigned short)(w16[j] & 0xffffu);
        xs[j * 2 + 1][t] = (unsigned short)(w16[j] >> 16);
      }
      unsigned w16b[8] = {r0.x, r0.y, r0.z, r0.w, r1.x, r1.y, r1.z, r1.w};
      #pragma unroll
      for (int j = 0; j < 8; ++j){
        xs[16 + j * 2][t]     = (unsigned short)(w16b[j] & 0xffffu);
        xs[16 + j * 2 + 1][t] = (unsigned short)(w16b[j] >> 16);
      }
    }
    __syncthreads();
    #pragma unroll 4
    for (int k = 0; k < 32; ++k){
      float xv[4];
      #pragma unroll
      for (int i = 0; i < 4; ++i) xv[i] = __uint_as_float(((unsigned)xs[k][ng + 64 * i]) << 16);
      float wv[10];
      #pragma unroll
      for (int j = 0; j < 10; ++j) wv[j] = ws[k0 + k][cg * 10 + j];
      #pragma unroll
      for (int i = 0; i < 4; ++i)
        #pragma unroll
        for (int j = 0; j < 10; ++j) acc[i][j] = fmaf(xv[i], wv[j], acc[i][j]);
    }
  }
  float asl[10], adl[10];
  #pragma unroll
  for (int j = 0; j < 10; ++j){ asl[j] = asw2[cg * 10 + j]; adl[j] = adw2[cg * 10 + j]; }
  #pragma unroll
  for (int i = 0; i < 4; ++i){
    float ssi = 0.f, ddi = 0.f;
    #pragma unroll
    for (int j = 0; j < 10; ++j){
      ssi = fmaf(acc[i][j], asl[j], ssi);
      ddi = fmaf(acc[i][j], adl[j], ddi);
    }
    atomicAdd(&ssb[ng + 64 * i], ssi);
    atomicAdd(&ddb[ng + 64 * i], ddi);
  }
  __syncthreads();
  unsigned char* RB = (unsigned char*)xs;
  #pragma unroll
  for (int i = 0; i < 4; ++i){
    int row = ng + 64 * i;
    unsigned char* dst = &RB[row * 64 + cg * 10];
    #pragma unroll
    for (int j = 0; j < 10; j += 2){
      int p2 = __builtin_amdgcn_cvt_pk_fp8_f32(acc[i][j], acc[i][j + 1], 0, 0);
      dst[j]     = (unsigned char)(p2 & 0xff);
      dst[j + 1] = (unsigned char)((p2 >> 8) & 0xff);
    }
  }
  *(float*)&RB[t * 64 + 40] = ssb[t];
  __syncthreads();
  {
    int gn = node0 + t;
    if (gn < n){
      a_d[gn] = ddb[t];
      uint4* drow = (uint4*)(h2q + (size_t)gn * 64);
      const uint4* srow = (const uint4*)&RB[t * 64];
      drow[0] = srow[0]; drow[1] = srow[1]; drow[2] = srow[2]; drow[3] = srow[3];
    }
  }
}

// ---- agg2: 2 nodes/wave, 4 edge-groups x 8 lanes per node (uint2 = 8 ch/lane) ----
__global__ __launch_bounds__(256) void k_agg2(const unsigned char* __restrict__ h2q,
    const float* __restrict__ a_d, const int* __restrict__ col,
    const int* __restrict__ excl, const int* __restrict__ deg,
    const float* __restrict__ b2, float* __restrict__ out, int n){
  int tl = threadIdx.x & 63;
  int half = tl >> 5;
  int node = blockIdx.x * 8 + (threadIdx.x >> 6) * 2 + half;
  if (node >= n) return;
  int lt = tl & 31;
  int g = lt >> 3, il = lt & 7;
  int hbase = tl & 32;                     // lane base of this half
  bool act = il < 5;                       // channels 8il..8il+7 (< 40)
  float adn = a_d[node];
  float ac[8];
  #pragma unroll
  for (int j = 0; j < 8; ++j) ac[j] = 0.f;
  float denom = 0.f;
  if (g == 0){
    uint2 hv = *(const uint2*)(h2q + (size_t)node * 64 + il * 8);
    float asf = __uint_as_float(__shfl(hv.x, hbase + 5));
    float wSelf = lrelu_exp(asf + adn);
    uint2 mv = act ? hv : make_uint2(0u, 0u);
    f32x2 l0 = __builtin_amdgcn_cvt_pk_f32_fp8((int)mv.x, false);
    f32x2 h0 = __builtin_amdgcn_cvt_pk_f32_fp8((int)mv.x, true);
    f32x2 l1 = __builtin_amdgcn_cvt_pk_f32_fp8((int)mv.y, false);
    f32x2 h1 = __builtin_amdgcn_cvt_pk_f32_fp8((int)mv.y, true);
    ac[0] = wSelf * l0[0]; ac[1] = wSelf * l0[1]; ac[2] = wSelf * h0[0]; ac[3] = wSelf * h0[1];
    ac[4] = wSelf * l1[0]; ac[5] = wSelf * l1[1]; ac[6] = wSelf * h1[0]; ac[7] = wSelf * h1[1];
    denom = wSelf;
  }
  int pp = excl[node];
  int end = pp + deg[node];
  int bsrc = hbase + (g << 3) + 5;         // a_s broadcast source lane
  for (; pp + 16 <= end; pp += 16){
    int s[4]; uint2 v[4];
    #pragma unroll
    for (int u = 0; u < 4; ++u) s[u] = col[pp + 4 * u + g];
    #pragma unroll
    for (int u = 0; u < 4; ++u) v[u] = *(const uint2*)(h2q + (size_t)s[u] * 64 + il * 8);
    #pragma unroll
    for (int u = 0; u < 4; ++u){
      float asf = __uint_as_float(__shfl(v[u].x, bsrc));
      float w = lrelu_exp(asf + adn);
      uint2 mv = act ? v[u] : make_uint2(0u, 0u);
      f32x2 l0 = __builtin_amdgcn_cvt_pk_f32_fp8((int)mv.x, false);
      f32x2 h0 = __builtin_amdgcn_cvt_pk_f32_fp8((int)mv.x, true);
      f32x2 l1 = __builtin_amdgcn_cvt_pk_f32_fp8((int)mv.y, false);
      f32x2 h1 = __builtin_amdgcn_cvt_pk_f32_fp8((int)mv.y, true);
      ac[0] = fmaf(w, l0[0], ac[0]); ac[1] = fmaf(w, l0[1], ac[1]);
      ac[2] = fmaf(w, h0[0], ac[2]); ac[3] = fmaf(w, h0[1], ac[3]);
      ac[4] = fmaf(w, l1[0], ac[4]); ac[5] = fmaf(w, l1[1], ac[5]);
      ac[6] = fmaf(w, h1[0], ac[6]); ac[7] = fmaf(w, h1[1], ac[7]);
      denom += w;
    }
  }
  for (; pp + 4 <= end; pp += 4){
    int s0 = col[pp + g];
    uint2 v0 = *(const uint2*)(h2q + (size_t)s0 * 64 + il * 8);
    float asf = __uint_as_float(__shfl(v0.x, bsrc));
    float w = lrelu_exp(asf + adn);
    uint2 mv = act ? v0 : make_uint2(0u, 0u);
    f32x2 l0 = __builtin_amdgcn_cvt_pk_f32_fp8((int)mv.x, false);
    f32x2 h0 = __builtin_amdgcn_cvt_pk_f32_fp8((int)mv.x, true);
    f32x2 l1 = __builtin_amdgcn_cvt_pk_f32_fp8((int)mv.y, false);
    f32x2 h1 = __builtin_amdgcn_cvt_pk_f32_fp8((int)mv.y, true);
    ac[0] = fmaf(w, l0[0], ac[0]); ac[1] = fmaf(w, l0[1], ac[1]);
    ac[2] = fmaf(w, h0[0], ac[2]); ac[3] = fmaf(w, h0[1], ac[3]);
    ac[4] = fmaf(w, l1[0], ac[4]); ac[5] = fmaf(w, l1[1], ac[5]);
    ac[6] = fmaf(w, h1[0], ac[6]); ac[7] = fmaf(w, h1[1], ac[7]);
    denom += w;
  }
  if (pp + g < end){
    int s0 = col[pp + g];
    uint2 v0 = *(const uint2*)(h2q + (size_t)s0 * 64 + il * 8);
    float asf = __uint_as_float(__shfl(v0.x, bsrc));
    float w = lrelu_exp(asf + adn);
    uint2 mv = act ? v0 : make_uint2(0u, 0u);
    f32x2 l0 = __builtin_amdgcn_cvt_pk_f32_fp8((int)mv.x, false);
    f32x2 h0 = __builtin_amdgcn_cvt_pk_f32_fp8((int)mv.x, true);
    f32x2 l1 = __builtin_amdgcn_cvt_pk_f32_fp8((int)mv.y, false);
    f32x2 h1 = __builtin_amdgcn_cvt_pk_f32_fp8((int)mv.y, true);
    ac[0] = fmaf(w, l0[0], ac[0]); ac[1] = fmaf(w, l0[1], ac[1]);
    ac[2] = fmaf(w, h0[0], ac[2]); ac[3] = fmaf(w, h0[1], ac[3]);
    ac[4] = fmaf(w, l1[0], ac[4]); ac[5] = fmaf(w, l1[1], ac[5]);
    ac[6] = fmaf(w, h1[0], ac[6]); ac[7] = fmaf(w, h1[1], ac[7]);
    denom += w;
  }
  #pragma unroll
  for (int off = 8; off <= 16; off <<= 1){
    #pragma unroll
    for (int j = 0; j < 8; ++j) ac[j] += __shfl_xor(ac[j], off);
    denom += __shfl_xor(denom, off);
  }
  float inv = 1.0f / denom;
  float vv[8];
  #pragma unroll
  for (int j = 0; j < 8; ++j){
    float bbj = act ? b2[il * 8 + j] : 0.f;
    vv[j] = act ? fmaf(ac[j], inv, bbj) : -1e30f;
  }
  float m = vv[0];
  #pragma unroll
  for (int j = 1; j < 8; ++j) m = fmaxf(m, vv[j]);
  #pragma unroll
  for (int off = 4; off >= 1; off >>= 1) m = fmaxf(m, __shfl_xor(m, off));
  float S = 0.f;
  if (act){
    #pragma unroll
    for (int j = 0; j < 8; ++j) S += __expf(vv[j] - m);
  }
  #pragma unroll
  for (int off = 4; off >= 1; off >>= 1) S += __shfl_xor(S, off);
  float ls = __logf(S);
  if (act && g == 0){
    float4 o0 = make_float4(vv[0] - m - ls, vv[1] - m - ls, vv[2] - m - ls, vv[3] - m - ls);
    float4 o1 = make_float4(vv[4] - m - ls, vv[5] - m - ls, vv[6] - m - ls, vv[7] - m - ls);
    *(float4*)(out + (size_t)node * 40 + il * 8)     = o0;
    *(float4*)(out + (size_t)node * 40 + il * 8 + 4) = o1;
  }
}

extern "C" void kernel_launch(void* const* d_in, const int* in_sizes, int n_in,
                              void* d_out, int out_size, void* d_ws, size_t ws_size,
                              hipStream_t stream){
  const float* x    = (const float*)d_in[0];
  const int*   ei   = (const int*)d_in[1];          // int32 (jax x64 disabled)
  const float* W1   = (const float*)d_in[2];
  const float* as1w = (const float*)d_in[3];
  const float* ad1w = (const float*)d_in[4];
  const float* b1   = (const float*)d_in[5];
  const float* W2   = (const float*)d_in[6];
  const float* as2w = (const float*)d_in[7];
  const float* ad2w = (const float*)d_in[8];
  const float* b2   = (const float*)d_in[9];
  float* out = (float*)d_out;
  const int N = in_sizes[0] / 128;
  const int E = in_sizes[1] / 2;

  const int NBK = (N + 255) / 256;
  const int B   = (E + 8191) / 8192;
  const int total = NBK * B;
  const int nsc = (total + 2047) / 2048;

  char* p = (char*)d_ws;
  auto alloc = [&](size_t bytes) -> void* {
    void* r = (void*)p;
    p += (bytes + 511) & ~(size_t)511;
    return r;
  };
  int*            deg      = (int*)           alloc((size_t)N * 4);
  int*            excl     = (int*)           alloc((size_t)N * 4);
  int*            counts   = (int*)           alloc((size_t)total * 4);
  int*            bstart   = (int*)           alloc((size_t)(NBK + 1) * 4);
  int*            partials = (int*)           alloc(64 * 4);
  int2*           pairs    = (int2*)          alloc((size_t)E * 8);
  int*            col      = (int*)           alloc((size_t)E * 4);
  float*          a_s1     = (float*)         alloc((size_t)N * 8 * 4);
  float*          a_d1     = (float*)         alloc((size_t)N * 8 * 4);
  unsigned short* out1b    = (unsigned short*)alloc((size_t)N * 128 * 2);
  unsigned char*  h1q      = (unsigned char*) alloc((size_t)N * 128);
  unsigned char*  h2q  = h1q;
  float*          a_d2 = (float*)(h1q + (size_t)N * 64 + 256);

  int nG1 = (N + 127) / 128;

  k_gemm1 <<<nG1, 256, 0, stream>>>(x, W1, as1w, ad1w, h1q, a_s1, a_d1, N);
  k_cnt   <<<B, 256, 0, stream>>>(ei, E, N, counts, B, NBK);
  k_s1    <<<nsc, 256, 0, stream>>>(counts, total, partials);
  k_s2    <<<1, 64, 0, stream>>>(partials, nsc, bstart, NBK);
  k_s3    <<<(total + 255) / 256, 256, 0, stream>>>(counts, total, partials, B, bstart);
  k_bscat <<<B, 256, 0, stream>>>(ei, E, N, counts, B, pairs, NBK);
  k_bucket<<<NBK, 256, 0, stream>>>(pairs, bstart, N, deg, excl, col);
  k_agg1  <<<(N + 7) / 8, 256, 0, stream>>>(h1q, a_s1, a_d1, col, excl, deg, b1, out1b, N);
  k_gemm2a<<<(N + 255) / 256, 256, 0, stream>>>(out1b, W2, as2w, ad2w, h2q, a_d2, N);
  k_agg2  <<<(N + 7) / 8, 256, 0, stream>>>(h2q, a_d2, col, excl, deg, b2, out, N);
}